// Round 2
// baseline (31720.572 us; speedup 1.0000x reference)
//
#include <hip/hip_runtime.h>
#include <hip/hip_bf16.h>
#include <stdint.h>

// Problem dims
#define Bn 128
#define Tn 512
#define En 512
#define Hn 2048
#define Vn 32000
#define R0 8           // h0 ring depth
#define R1 4           // h1 ring depth
#define HSLOT (Bn*Hn)  // elements per h slot

typedef float f32x4 __attribute__((ext_vector_type(4)));
typedef short bf16x8 __attribute__((ext_vector_type(8)));

__device__ __forceinline__ unsigned short f2b(float f) {
  // round-to-nearest-even bf16
  uint32_t x = __builtin_bit_cast(uint32_t, f);
  uint32_t r = x + 0x7FFFu + ((x >> 16) & 1u);
  return (unsigned short)(r >> 16);
}

__device__ __forceinline__ void wait_ge(uint32_t* p, uint32_t tgt) {
  while (__hip_atomic_load(p, __ATOMIC_RELAXED, __HIP_MEMORY_SCOPE_AGENT) < tgt) {
    __builtin_amdgcn_s_sleep(2);
  }
  __builtin_amdgcn_fence(__ATOMIC_ACQUIRE, "agent");
}
__device__ __forceinline__ void signal_add(uint32_t* p) {
  __hip_atomic_fetch_add(p, 1u, __ATOMIC_RELEASE, __HIP_MEMORY_SCOPE_AGENT);
}
__device__ __forceinline__ void signal_store(uint32_t* p, uint32_t v) {
  __hip_atomic_store(p, v, __ATOMIC_RELEASE, __HIP_MEMORY_SCOPE_AGENT);
}

// ---------------- init / pack kernels ----------------

__global__ void zero3(uint32_t* a, int na, uint32_t* b, int nb, uint32_t* c, int nc) {
  int i = blockIdx.x * 256 + threadIdx.x;
  if (i < na) a[i] = 0u;
  if (i < nb) b[i] = 0u;
  if (i < nc) c[i] = 0u;
}

__global__ void pack_bias(const float* bih0, const float* bhh0,
                          const float* bih1, const float* bhh1,
                          float* bias0, float* bias1) {
  int i = blockIdx.x * 256 + threadIdx.x;  // 2048 threads
  bias0[i] = bih0[i] + bhh0[i];
  bias1[i] = bih1[i] + bhh1[i];
}

// A-images: 128 WGs x 5120 packets of 16B. packet p=(kt*4+ct)*64+l
// element j of lane l: W[col = g*64+ct*16+(l&15)][kv = s*640+kt*32+(l>>4)*8+j]
// kv<512 -> Wih0 [H x E], else Whh0 [H x H] at kv-512
__global__ void pack_imgA(const float* __restrict__ Wih0, const float* __restrict__ Whh0,
                          uint4* __restrict__ imgA) {
  int tid = blockIdx.x * 256 + threadIdx.x;   // 655360 total
  int wg = tid / 5120;
  int p  = tid - wg * 5120;
  int l = p & 63;
  int ckt = p >> 6;
  int ct = ckt & 3, kt = ckt >> 2;
  int g = wg >> 2, s = wg & 3;
  int col = g * 64 + ct * 16 + (l & 15);
  int kv0 = s * 640 + kt * 32 + (l >> 4) * 8;
  const float* src = (kv0 < 512) ? (Wih0 + (size_t)col * En + kv0)
                                 : (Whh0 + (size_t)col * Hn + (kv0 - 512));
  unsigned short o[8];
#pragma unroll
  for (int j = 0; j < 8; ++j) o[j] = f2b(src[j]);
  imgA[tid] = *reinterpret_cast<uint4*>(o);
}

// B-images: 128 WGs x 8192 packets. kv = s*1024+kt*32+..; kv<2048 -> Wih1 else Whh1
__global__ void pack_imgB(const float* __restrict__ Wih1, const float* __restrict__ Whh1,
                          uint4* __restrict__ imgB) {
  int tid = blockIdx.x * 256 + threadIdx.x;   // 1048576 total
  int wg = tid >> 13;
  int p  = tid & 8191;
  int l = p & 63;
  int ckt = p >> 6;
  int ct = ckt & 3, kt = ckt >> 2;
  int g = wg >> 2, s = wg & 3;
  int col = g * 64 + ct * 16 + (l & 15);
  int kv0 = s * 1024 + kt * 32 + (l >> 4) * 8;
  const float* src = (kv0 < 2048) ? (Wih1 + (size_t)col * Hn + kv0)
                                  : (Whh1 + (size_t)col * Hn + (kv0 - 2048));
  unsigned short o[8];
#pragma unroll
  for (int j = 0; j < 8; ++j) o[j] = f2b(src[j]);
  imgB[tid] = *reinterpret_cast<uint4*>(o);
}

// W1 images: 32 groups of 16 cols, K=2048: 4096 packets each (kt*64+l)
__global__ void pack_imgW1(const float* __restrict__ W1, uint4* __restrict__ img) {
  int tid = blockIdx.x * 256 + threadIdx.x;  // 131072
  int grp = tid >> 12;
  int p = tid & 4095;
  int l = p & 63;
  int kt = p >> 6;
  int col = grp * 16 + (l & 15);
  int k0 = kt * 32 + (l >> 4) * 8;
  const float* src = W1 + (size_t)col * Hn + k0;
  unsigned short o[8];
#pragma unroll
  for (int j = 0; j < 8; ++j) o[j] = f2b(src[j]);
  img[tid] = *reinterpret_cast<uint4*>(o);
}

// W2 images: 500 groups of 64 cols, K=512: 4096 packets each ((kt*4+ct)*64+l)
__global__ void pack_imgW2(const float* __restrict__ W2, uint4* __restrict__ img) {
  int tid = blockIdx.x * 256 + threadIdx.x;  // 2048000
  int grp = tid >> 12;
  int p = tid & 4095;
  int l = p & 63;
  int ckt = p >> 6;
  int ct = ckt & 3, kt = ckt >> 2;
  int col = grp * 64 + ct * 16 + (l & 15);
  int k0 = kt * 32 + (l >> 4) * 8;
  const float* src = W2 + (size_t)col * En + k0;
  unsigned short o[8];
#pragma unroll
  for (int j = 0; j < 8; ++j) o[j] = f2b(src[j]);
  img[tid] = *reinterpret_cast<uint4*>(o);
}

// x_all[t][b][e] bf16 = emb[ids[b][t]][e]
__global__ void gather_x(const int* __restrict__ ids, const float* __restrict__ emb,
                         uint4* __restrict__ xall) {
  int tid = blockIdx.x * 256 + threadIdx.x;  // 4194304
  int t = tid >> 13;
  int r = tid & 8191;
  int b = r >> 6;
  int e8 = r & 63;
  int id = ids[b * Tn + t];
  const float* src = emb + (size_t)id * En + e8 * 8;
  unsigned short o[8];
#pragma unroll
  for (int j = 0; j < 8; ++j) o[j] = f2b(src[j]);
  xall[tid] = *reinterpret_cast<uint4*>(o);
}

// ---------------- persistent RNN kernel ----------------
// blocks 0..127  : role A (h0). group g=blk>>2 owns cols [g*64,g*64+64), split s=blk&3
//                  K-chunk = virtual k [s*640, s*640+640) of [x_t(512) ; h0(t-1)(2048)]
// blocks 128..255: role B (h1). K-chunk = [s*1024, ..) of [h0(t)(2048) ; h1(t-1)(2048)]
//
// pbuf overwrite discipline: a partial may write pbuf for step t only when its
// group's reducer has consumed step t-1. Role A s=1..3: implied by
// cnt_h0 >= 32*t (own reducer signaled t-1 after reading pbuf). Role B s=2,3:
// implied by cnt_h1 >= 32*t. Role B s=1 gates only on cnt_h0 otherwise, and
// role A can run R0 steps ahead -> explicit wait on cnt_h1 >= 32*t (race fix, R1).
__global__ __launch_bounds__(256) void rnn_persist(
    const uint4* __restrict__ imgA, const uint4* __restrict__ imgB,
    const unsigned short* __restrict__ xall,
    unsigned short* __restrict__ h0ring, unsigned short* __restrict__ h1ring,
    float* __restrict__ pbufA, float* __restrict__ pbufB,
    const float* __restrict__ bias0, const float* __restrict__ bias1,
    uint32_t* flags) {
  __shared__ uint4 smem[8192];  // 128 KiB -> 1 WG/CU, 256 WGs = 256 CUs, all resident
  const int tid = threadIdx.x;
  const int w = tid >> 6;
  const int l = tid & 63;
  const int l15 = l & 15;
  const int kq = l >> 4;
  const int blk = blockIdx.x;
  uint32_t* cnt_h0 = flags + 0;
  uint32_t* cnt_h1 = flags + 32;
  uint32_t* pflagA = flags + 256;
  uint32_t* pflagB = flags + 512;

  const bool roleA = (blk < 128);
  {
    const uint4* src = roleA ? (imgA + (size_t)blk * 5120) : (imgB + (size_t)(blk - 128) * 8192);
    const int n = roleA ? 5120 : 8192;
    for (int i = tid; i < n; i += 256) smem[i] = src[i];
  }
  __syncthreads();
  const bf16x8* wlds = reinterpret_cast<const bf16x8*>(smem);
  const int row0 = w * 32 + l15;

  if (roleA) {
    const int g = blk >> 2, s = blk & 3;
    const int colbase = g * 64;
    for (int t = 0; t < Tn; ++t) {
      wait_ge(cnt_h0, 32u * (uint32_t)t);  // h0[t-1] complete (also: own reducer consumed pbuf[t-1])
      const unsigned short* h0prev = h0ring + (size_t)((t + R0 - 1) % R0) * HSLOT;
      const unsigned short* xt = xall + (size_t)t * (Bn * En);
      f32x4 acc[2][4];
#pragma unroll
      for (int mt = 0; mt < 2; ++mt)
#pragma unroll
        for (int ct = 0; ct < 4; ++ct) acc[mt][ct] = (f32x4){0.f, 0.f, 0.f, 0.f};
#pragma unroll 4
      for (int kt = 0; kt < 20; ++kt) {
        const int kv = s * 640 + kt * 32;
        const unsigned short* ap;
        int as;
        if (kv < 512) { ap = xt + kv; as = En; }
        else          { ap = h0prev + (kv - 512); as = Hn; }
        bf16x8 af0 = *reinterpret_cast<const bf16x8*>(ap + (size_t)row0 * as + kq * 8);
        bf16x8 af1 = *reinterpret_cast<const bf16x8*>(ap + (size_t)(row0 + 16) * as + kq * 8);
#pragma unroll
        for (int ct = 0; ct < 4; ++ct) {
          bf16x8 bf = wlds[(kt * 4 + ct) * 64 + l];
          acc[0][ct] = __builtin_amdgcn_mfma_f32_16x16x32_bf16(af0, bf, acc[0][ct], 0, 0, 0);
          acc[1][ct] = __builtin_amdgcn_mfma_f32_16x16x32_bf16(af1, bf, acc[1][ct], 0, 0, 0);
        }
      }
      if (s != 0) {
        float* slot = pbufA + (size_t)blk * 8192;
#pragma unroll
        for (int mt = 0; mt < 2; ++mt)
#pragma unroll
          for (int ct = 0; ct < 4; ++ct)
            *reinterpret_cast<f32x4*>(slot + ((w * 8 + mt * 4 + ct) * 256 + l * 4)) = acc[mt][ct];
        __syncthreads();
        if (tid == 0) signal_store(&pflagA[blk], (uint32_t)(t + 1));
      } else {
        wait_ge(&pflagA[blk + 1], (uint32_t)(t + 1));
        wait_ge(&pflagA[blk + 2], (uint32_t)(t + 1));
        wait_ge(&pflagA[blk + 3], (uint32_t)(t + 1));
        const float* p1 = pbufA + (size_t)(blk + 1) * 8192;
        const float* p2 = pbufA + (size_t)(blk + 2) * 8192;
        const float* p3 = pbufA + (size_t)(blk + 3) * 8192;
        if (t + 1 > R0) wait_ge(cnt_h1, 32u * (uint32_t)(t + 1 - R0));  // ring safety
        unsigned short* h0cur = h0ring + (size_t)(t % R0) * HSLOT;
#pragma unroll
        for (int mt = 0; mt < 2; ++mt) {
#pragma unroll
          for (int ct = 0; ct < 4; ++ct) {
            const int base = (w * 8 + mt * 4 + ct) * 256 + l * 4;
            f32x4 sum = acc[mt][ct];
            sum += *reinterpret_cast<const f32x4*>(p1 + base);
            sum += *reinterpret_cast<const f32x4*>(p2 + base);
            sum += *reinterpret_cast<const f32x4*>(p3 + base);
            const int col = colbase + ct * 16 + l15;
            const float bb = bias0[col];
#pragma unroll
            for (int r = 0; r < 4; ++r) {
              float v = tanhf(sum[r] + bb);
              const int row = w * 32 + mt * 16 + kq * 4 + r;
              h0cur[(size_t)row * Hn + col] = f2b(v);
            }
          }
        }
        __syncthreads();
        if (tid == 0) signal_add(cnt_h0);
      }
    }
  } else {
    const int bb = blk - 128;
    const int g = bb >> 2, s = bb & 3;
    const int colbase = g * 64;
    for (int t = 0; t < Tn; ++t) {
      if (s < 2) {
        wait_ge(cnt_h0, 32u * (uint32_t)(t + 1));  // h0[t] complete
        // RACE FIX: s==1's pbuf overwrite was gated only on cnt_h0 (role A can
        // run R0 ahead) -> must also wait until own reducer consumed pbuf[t-1].
        if (s == 1 && t > 0) wait_ge(cnt_h1, 32u * (uint32_t)t);
      } else {
        wait_ge(cnt_h1, 32u * (uint32_t)t);        // h1[t-1] complete
      }
      const unsigned short* h0cur = h0ring + (size_t)(t % R0) * HSLOT;
      const unsigned short* h1prev = h1ring + (size_t)((t + R1 - 1) % R1) * HSLOT;
      const unsigned short* apbase;
      if (s == 0)      apbase = h0cur;
      else if (s == 1) apbase = h0cur + 1024;
      else if (s == 2) apbase = h1prev;
      else             apbase = h1prev + 1024;
      f32x4 acc[2][4];
#pragma unroll
      for (int mt = 0; mt < 2; ++mt)
#pragma unroll
        for (int ct = 0; ct < 4; ++ct) acc[mt][ct] = (f32x4){0.f, 0.f, 0.f, 0.f};
#pragma unroll 4
      for (int kt = 0; kt < 32; ++kt) {
        const unsigned short* ap = apbase + kt * 32;
        bf16x8 af0 = *reinterpret_cast<const bf16x8*>(ap + (size_t)row0 * Hn + kq * 8);
        bf16x8 af1 = *reinterpret_cast<const bf16x8*>(ap + (size_t)(row0 + 16) * Hn + kq * 8);
#pragma unroll
        for (int ct = 0; ct < 4; ++ct) {
          bf16x8 bf = wlds[(kt * 4 + ct) * 64 + l];
          acc[0][ct] = __builtin_amdgcn_mfma_f32_16x16x32_bf16(af0, bf, acc[0][ct], 0, 0, 0);
          acc[1][ct] = __builtin_amdgcn_mfma_f32_16x16x32_bf16(af1, bf, acc[1][ct], 0, 0, 0);
        }
      }
      if (s != 0) {
        float* slot = pbufB + (size_t)bb * 8192;
#pragma unroll
        for (int mt = 0; mt < 2; ++mt)
#pragma unroll
          for (int ct = 0; ct < 4; ++ct)
            *reinterpret_cast<f32x4*>(slot + ((w * 8 + mt * 4 + ct) * 256 + l * 4)) = acc[mt][ct];
        __syncthreads();
        if (tid == 0) signal_store(&pflagB[bb], (uint32_t)(t + 1));
      } else {
        wait_ge(&pflagB[bb + 1], (uint32_t)(t + 1));
        wait_ge(&pflagB[bb + 2], (uint32_t)(t + 1));
        wait_ge(&pflagB[bb + 3], (uint32_t)(t + 1));
        const float* p1 = pbufB + (size_t)(bb + 1) * 8192;
        const float* p2 = pbufB + (size_t)(bb + 2) * 8192;
        const float* p3 = pbufB + (size_t)(bb + 3) * 8192;
        if (t + 2 > R1) wait_ge(cnt_h1, 32u * (uint32_t)(t + 2 - R1));  // ring safety
        unsigned short* h1cur = h1ring + (size_t)(t % R1) * HSLOT;
#pragma unroll
        for (int mt = 0; mt < 2; ++mt) {
#pragma unroll
          for (int ct = 0; ct < 4; ++ct) {
            const int base = (w * 8 + mt * 4 + ct) * 256 + l * 4;
            f32x4 sum = acc[mt][ct];
            sum += *reinterpret_cast<const f32x4*>(p1 + base);
            sum += *reinterpret_cast<const f32x4*>(p2 + base);
            sum += *reinterpret_cast<const f32x4*>(p3 + base);
            const int col = colbase + ct * 16 + l15;
            const float bb2 = bias1[col];
#pragma unroll
            for (int r = 0; r < 4; ++r) {
              float v = tanhf(sum[r] + bb2);
              const int row = w * 32 + mt * 16 + kq * 4 + r;
              h1cur[(size_t)row * Hn + col] = f2b(v);
            }
          }
        }
        __syncthreads();
        if (tid == 0) signal_add(cnt_h1);
      }
    }
  }
}

// ---------------- head ----------------
// a1 = relu(h1 @ W1.T + b1)  [128 x 512] bf16
__global__ __launch_bounds__(256) void head1(const uint4* __restrict__ imgW1,
                                             const unsigned short* __restrict__ h1f,
                                             const float* __restrict__ b1,
                                             unsigned short* __restrict__ a1) {
  __shared__ uint4 smem[4096];
  const int tid = threadIdx.x;
  const int w = tid >> 6, l = tid & 63, l15 = l & 15, kq = l >> 4;
  const int g = blockIdx.x;  // 32
  const uint4* src = imgW1 + (size_t)g * 4096;
  for (int i = tid; i < 4096; i += 256) smem[i] = src[i];
  __syncthreads();
  const bf16x8* wlds = reinterpret_cast<const bf16x8*>(smem);
  const int row0 = w * 32 + l15;
  f32x4 acc[2];
  acc[0] = (f32x4){0.f, 0.f, 0.f, 0.f};
  acc[1] = (f32x4){0.f, 0.f, 0.f, 0.f};
#pragma unroll 4
  for (int kt = 0; kt < 64; ++kt) {
    bf16x8 af0 = *reinterpret_cast<const bf16x8*>(h1f + (size_t)row0 * Hn + kt * 32 + kq * 8);
    bf16x8 af1 = *reinterpret_cast<const bf16x8*>(h1f + (size_t)(row0 + 16) * Hn + kt * 32 + kq * 8);
    bf16x8 bf = wlds[kt * 64 + l];
    acc[0] = __builtin_amdgcn_mfma_f32_16x16x32_bf16(af0, bf, acc[0], 0, 0, 0);
    acc[1] = __builtin_amdgcn_mfma_f32_16x16x32_bf16(af1, bf, acc[1], 0, 0, 0);
  }
  const int col = g * 16 + l15;
  const float bb = b1[col];
#pragma unroll
  for (int mt = 0; mt < 2; ++mt)
#pragma unroll
    for (int r = 0; r < 4; ++r) {
      float v = fmaxf(acc[mt][r] + bb, 0.f);
      const int row = w * 32 + mt * 16 + kq * 4 + r;
      a1[(size_t)row * En + col] = f2b(v);
    }
}

// out = a1 @ W2.T + b2  [128 x 32000] f32
__global__ __launch_bounds__(256) void head2(const uint4* __restrict__ imgW2,
                                             const unsigned short* __restrict__ a1,
                                             const float* __restrict__ b2,
                                             float* __restrict__ out) {
  __shared__ uint4 smem[4096];
  const int tid = threadIdx.x;
  const int w = tid >> 6, l = tid & 63, l15 = l & 15, kq = l >> 4;
  const int g = blockIdx.x;  // 500
  const uint4* src = imgW2 + (size_t)g * 4096;
  for (int i = tid; i < 4096; i += 256) smem[i] = src[i];
  __syncthreads();
  const bf16x8* wlds = reinterpret_cast<const bf16x8*>(smem);
  const int row0 = w * 32 + l15;
  f32x4 acc[2][4];
#pragma unroll
  for (int mt = 0; mt < 2; ++mt)
#pragma unroll
    for (int ct = 0; ct < 4; ++ct) acc[mt][ct] = (f32x4){0.f, 0.f, 0.f, 0.f};
#pragma unroll
  for (int kt = 0; kt < 16; ++kt) {
    bf16x8 af0 = *reinterpret_cast<const bf16x8*>(a1 + (size_t)row0 * En + kt * 32 + kq * 8);
    bf16x8 af1 = *reinterpret_cast<const bf16x8*>(a1 + (size_t)(row0 + 16) * En + kt * 32 + kq * 8);
#pragma unroll
    for (int ct = 0; ct < 4; ++ct) {
      bf16x8 bf = wlds[(kt * 4 + ct) * 64 + l];
      acc[0][ct] = __builtin_amdgcn_mfma_f32_16x16x32_bf16(af0, bf, acc[0][ct], 0, 0, 0);
      acc[1][ct] = __builtin_amdgcn_mfma_f32_16x16x32_bf16(af1, bf, acc[1][ct], 0, 0, 0);
    }
  }
#pragma unroll
  for (int mt = 0; mt < 2; ++mt)
#pragma unroll
    for (int ct = 0; ct < 4; ++ct) {
      const int col = g * 64 + ct * 16 + l15;
      const float bb = b2[col];
#pragma unroll
      for (int r = 0; r < 4; ++r) {
        const int row = w * 32 + mt * 16 + kq * 4 + r;
        out[(size_t)row * Vn + col] = acc[mt][ct][r] + bb;
      }
    }
}

// ---------------- launch ----------------
extern "C" void kernel_launch(void* const* d_in, const int* in_sizes, int n_in,
                              void* d_out, int out_size, void* d_ws, size_t ws_size,
                              hipStream_t stream) {
  (void)in_sizes; (void)n_in; (void)out_size;
  const int* ids    = (const int*)d_in[0];
  const float* emb  = (const float*)d_in[1];
  const float* Wih0 = (const float*)d_in[2];
  const float* Whh0 = (const float*)d_in[3];
  const float* bih0 = (const float*)d_in[4];
  const float* bhh0 = (const float*)d_in[5];
  const float* Wih1 = (const float*)d_in[6];
  const float* Whh1 = (const float*)d_in[7];
  const float* bih1 = (const float*)d_in[8];
  const float* bhh1 = (const float*)d_in[9];
  const float* W1   = (const float*)d_in[10];
  const float* b1   = (const float*)d_in[11];
  const float* W2   = (const float*)d_in[12];
  const float* b2   = (const float*)d_in[13];
  float* out = (float*)d_out;

  char* ws = (char*)d_ws;
  size_t o = 0;
  auto alloc = [&](size_t bytes) -> char* {
    char* p = ws + o;
    o += (bytes + 255) & ~(size_t)255;
    return p;
  };
  uint32_t* flags = (uint32_t*)alloc(4096);
  float* bias0 = (float*)alloc(Hn * 4);
  float* bias1 = (float*)alloc(Hn * 4);
  unsigned short* h0ring = (unsigned short*)alloc((size_t)R0 * HSLOT * 2);
  unsigned short* h1ring = (unsigned short*)alloc((size_t)R1 * HSLOT * 2);
  float* pbufA = (float*)alloc(128ull * 8192 * 4);
  float* pbufB = (float*)alloc(128ull * 8192 * 4);
  unsigned short* a1 = (unsigned short*)alloc((size_t)Bn * En * 2);
  uint4* imgA  = (uint4*)alloc(128ull * 5120 * 16);
  uint4* imgB  = (uint4*)alloc(128ull * 8192 * 16);
  uint4* imgW1 = (uint4*)alloc(32ull * 4096 * 16);
  uint4* imgW2 = (uint4*)alloc(500ull * 4096 * 16);
  uint4* xall  = (uint4*)alloc((size_t)Tn * Bn * En * 2);
  if (o > ws_size) return;  // workspace too small -> fail visibly (no OOB writes)

  zero3<<<512, 256, 0, stream>>>(flags, 1024,
                                 (uint32_t*)(h0ring + (size_t)(R0 - 1) * HSLOT), 131072,
                                 (uint32_t*)(h1ring + (size_t)(R1 - 1) * HSLOT), 131072);
  pack_bias<<<8, 256, 0, stream>>>(bih0, bhh0, bih1, bhh1, bias0, bias1);
  pack_imgA<<<2560, 256, 0, stream>>>(Wih0, Whh0, imgA);
  pack_imgB<<<4096, 256, 0, stream>>>(Wih1, Whh1, imgB);
  pack_imgW1<<<512, 256, 0, stream>>>(W1, imgW1);
  pack_imgW2<<<8000, 256, 0, stream>>>(W2, imgW2);
  gather_x<<<16384, 256, 0, stream>>>(ids, emb, xall);

  rnn_persist<<<256, 256, 0, stream>>>(imgA, imgB, (const unsigned short*)xall,
                                       h0ring, h1ring, pbufA, pbufB, bias0, bias1, flags);

  head1<<<32, 256, 0, stream>>>(imgW1, h1ring + (size_t)(511 % R1) * HSLOT, b1, a1);
  head2<<<500, 256, 0, stream>>>(imgW2, a1, b2, out);
}

// Round 3
// 15077.614 us; speedup vs baseline: 2.1038x; 2.1038x over previous
//
#include <hip/hip_runtime.h>
#include <hip/hip_bf16.h>
#include <stdint.h>

// Problem dims
#define Bn 128
#define Tn 512
#define En 512
#define Hn 2048
#define Vn 32000
#define R0 8           // h0 ring depth
#define R1 4           // h1 ring depth
#define HSLOT (Bn*Hn)  // elements per h slot

typedef float f32x4 __attribute__((ext_vector_type(4)));
typedef short bf16x8 __attribute__((ext_vector_type(8)));
typedef unsigned long long u64;

__device__ __forceinline__ unsigned short f2b(float f) {
  // round-to-nearest-even bf16
  uint32_t x = __builtin_bit_cast(uint32_t, f);
  uint32_t r = x + 0x7FFFu + ((x >> 16) & 1u);
  return (unsigned short)(r >> 16);
}

// ---- fence-free cross-XCD data movement: relaxed agent-scope atomics ----
// These bypass L1/L2 to the coherence point (MALL), so producer->consumer
// visibility needs NO buffer_wbl2/buffer_inv. Ordering data-before-flag is
// enforced by s_waitcnt vmcnt(0) + __syncthreads before the flag store.
union U16x8 { bf16x8 v; u64 q[2]; };
union F32x4u { f32x4 v; u64 q[2]; };

__device__ __forceinline__ bf16x8 ld_h(const unsigned short* p) {
  U16x8 u;
  u.q[0] = __hip_atomic_load((const u64*)p,     __ATOMIC_RELAXED, __HIP_MEMORY_SCOPE_AGENT);
  u.q[1] = __hip_atomic_load((const u64*)p + 1, __ATOMIC_RELAXED, __HIP_MEMORY_SCOPE_AGENT);
  return u.v;
}
__device__ __forceinline__ f32x4 ld_p(const float* p) {
  F32x4u u;
  u.q[0] = __hip_atomic_load((const u64*)p,     __ATOMIC_RELAXED, __HIP_MEMORY_SCOPE_AGENT);
  u.q[1] = __hip_atomic_load((const u64*)p + 1, __ATOMIC_RELAXED, __HIP_MEMORY_SCOPE_AGENT);
  return u.v;
}
__device__ __forceinline__ void st_p(float* p, f32x4 x) {
  F32x4u u; u.v = x;
  __hip_atomic_store((u64*)p,     u.q[0], __ATOMIC_RELAXED, __HIP_MEMORY_SCOPE_AGENT);
  __hip_atomic_store((u64*)p + 1, u.q[1], __ATOMIC_RELAXED, __HIP_MEMORY_SCOPE_AGENT);
}
__device__ __forceinline__ uint32_t ldf(const uint32_t* p) {
  return __hip_atomic_load(p, __ATOMIC_RELAXED, __HIP_MEMORY_SCOPE_AGENT);
}
__device__ __forceinline__ void stf(uint32_t* p, uint32_t v) {
  __hip_atomic_store(p, v, __ATOMIC_RELAXED, __HIP_MEMORY_SCOPE_AGENT);
}
__device__ __forceinline__ void drain_then_sync() {
  asm volatile("s_waitcnt vmcnt(0)" ::: "memory");
  __syncthreads();
}

// ---------------- init / pack kernels ----------------

__global__ void zero3(uint32_t* a, int na, uint32_t* b, int nb, uint32_t* c, int nc) {
  int i = blockIdx.x * 256 + threadIdx.x;
  if (i < na) a[i] = 0u;
  if (i < nb) b[i] = 0u;
  if (i < nc) c[i] = 0u;
}

__global__ void pack_bias(const float* bih0, const float* bhh0,
                          const float* bih1, const float* bhh1,
                          float* bias0, float* bias1) {
  int i = blockIdx.x * 256 + threadIdx.x;  // 2048 threads
  bias0[i] = bih0[i] + bhh0[i];
  bias1[i] = bih1[i] + bhh1[i];
}

// A-images: 128 WGs x 5120 packets of 16B. packet p=(kt*4+ct)*64+l
// element j of lane l: W[col = g*64+ct*16+(l&15)][kv = s*640+kt*32+(l>>4)*8+j]
// kv<512 -> Wih0 [H x E], else Whh0 [H x H] at kv-512
__global__ void pack_imgA(const float* __restrict__ Wih0, const float* __restrict__ Whh0,
                          uint4* __restrict__ imgA) {
  int tid = blockIdx.x * 256 + threadIdx.x;   // 655360 total
  int wg = tid / 5120;
  int p  = tid - wg * 5120;
  int l = p & 63;
  int ckt = p >> 6;
  int ct = ckt & 3, kt = ckt >> 2;
  int g = wg >> 2, s = wg & 3;
  int col = g * 64 + ct * 16 + (l & 15);
  int kv0 = s * 640 + kt * 32 + (l >> 4) * 8;
  const float* src = (kv0 < 512) ? (Wih0 + (size_t)col * En + kv0)
                                 : (Whh0 + (size_t)col * Hn + (kv0 - 512));
  unsigned short o[8];
#pragma unroll
  for (int j = 0; j < 8; ++j) o[j] = f2b(src[j]);
  imgA[tid] = *reinterpret_cast<uint4*>(o);
}

// B-images: 128 WGs x 8192 packets. kv = s*1024+kt*32+..; kv<2048 -> Wih1 else Whh1
__global__ void pack_imgB(const float* __restrict__ Wih1, const float* __restrict__ Whh1,
                          uint4* __restrict__ imgB) {
  int tid = blockIdx.x * 256 + threadIdx.x;   // 1048576 total
  int wg = tid >> 13;
  int p  = tid & 8191;
  int l = p & 63;
  int ckt = p >> 6;
  int ct = ckt & 3, kt = ckt >> 2;
  int g = wg >> 2, s = wg & 3;
  int col = g * 64 + ct * 16 + (l & 15);
  int kv0 = s * 1024 + kt * 32 + (l >> 4) * 8;
  const float* src = (kv0 < 2048) ? (Wih1 + (size_t)col * Hn + kv0)
                                  : (Whh1 + (size_t)col * Hn + (kv0 - 2048));
  unsigned short o[8];
#pragma unroll
  for (int j = 0; j < 8; ++j) o[j] = f2b(src[j]);
  imgB[tid] = *reinterpret_cast<uint4*>(o);
}

// W1 images: 32 groups of 16 cols, K=2048: 4096 packets each (kt*64+l)
__global__ void pack_imgW1(const float* __restrict__ W1, uint4* __restrict__ img) {
  int tid = blockIdx.x * 256 + threadIdx.x;  // 131072
  int grp = tid >> 12;
  int p = tid & 4095;
  int l = p & 63;
  int kt = p >> 6;
  int col = grp * 16 + (l & 15);
  int k0 = kt * 32 + (l >> 4) * 8;
  const float* src = W1 + (size_t)col * Hn + k0;
  unsigned short o[8];
#pragma unroll
  for (int j = 0; j < 8; ++j) o[j] = f2b(src[j]);
  img[tid] = *reinterpret_cast<uint4*>(o);
}

// W2 images: 500 groups of 64 cols, K=512: 4096 packets each ((kt*4+ct)*64+l)
__global__ void pack_imgW2(const float* __restrict__ W2, uint4* __restrict__ img) {
  int tid = blockIdx.x * 256 + threadIdx.x;  // 2048000
  int grp = tid >> 12;
  int p = tid & 4095;
  int l = p & 63;
  int ckt = p >> 6;
  int ct = ckt & 3, kt = ckt >> 2;
  int col = grp * 64 + ct * 16 + (l & 15);
  int k0 = kt * 32 + (l >> 4) * 8;
  const float* src = W2 + (size_t)col * En + k0;
  unsigned short o[8];
#pragma unroll
  for (int j = 0; j < 8; ++j) o[j] = f2b(src[j]);
  img[tid] = *reinterpret_cast<uint4*>(o);
}

// x_all[t][b][e] bf16 = emb[ids[b][t]][e]
__global__ void gather_x(const int* __restrict__ ids, const float* __restrict__ emb,
                         uint4* __restrict__ xall) {
  int tid = blockIdx.x * 256 + threadIdx.x;  // 4194304
  int t = tid >> 13;
  int r = tid & 8191;
  int b = r >> 6;
  int e8 = r & 63;
  int id = ids[b * Tn + t];
  const float* src = emb + (size_t)id * En + e8 * 8;
  unsigned short o[8];
#pragma unroll
  for (int j = 0; j < 8; ++j) o[j] = f2b(src[j]);
  xall[tid] = *reinterpret_cast<uint4*>(o);
}

// ---------------- persistent RNN kernel ----------------
// blocks 0..127  : role A (h0). group g=blk>>2 owns cols [g*64,g*64+64), split s=blk&3
//                  K-chunk = virtual k [s*640, s*640+640) of [x_t(512) ; h0(t-1)(2048)]
// blocks 128..255: role B (h1). K-chunk = [s*1024, ..) of [h0(t)(2048) ; h1(t-1)(2048)]
//
// Flags (all per-block, stored/polled with relaxed agent atomics, NO fences):
//   fA0[32]  : group g's reducer finished step v-1  (h0[v-1] complete)
//   fB0[32]  : group g's reducer finished step v-1  (h1[v-1] complete)
//   fApart[128], fBpart[128]: partial block wrote pbuf for step v-1
// Wait conditions are the round-2 audited set (incl. s==1 race fix + ring checks),
// re-expressed over flag arrays with __syncthreads_and spins.
__global__ __launch_bounds__(256) void rnn_persist(
    const uint4* __restrict__ imgA, const uint4* __restrict__ imgB,
    const unsigned short* __restrict__ xall,
    unsigned short* __restrict__ h0ring, unsigned short* __restrict__ h1ring,
    float* __restrict__ pbufA, float* __restrict__ pbufB,
    const float* __restrict__ bias0, const float* __restrict__ bias1,
    uint32_t* flags) {
  __shared__ uint4 smem[8192];  // 128 KiB -> 1 WG/CU, 256 WGs = 256 CUs, all resident
  const int tid = threadIdx.x;
  const int w = tid >> 6;
  const int l = tid & 63;
  const int l15 = l & 15;
  const int kq = l >> 4;
  const int blk = blockIdx.x;
  uint32_t* fA0    = flags + 0;
  uint32_t* fB0    = flags + 32;
  uint32_t* fApart = flags + 64;
  uint32_t* fBpart = flags + 192;

  const bool roleA = (blk < 128);
  {
    const uint4* src = roleA ? (imgA + (size_t)blk * 5120) : (imgB + (size_t)(blk - 128) * 8192);
    const int n = roleA ? 5120 : 8192;
    for (int i = tid; i < n; i += 256) smem[i] = src[i];
  }
  __syncthreads();
  const bf16x8* wlds = reinterpret_cast<const bf16x8*>(smem);
  const int row0 = w * 32 + l15;

  if (roleA) {
    const int g = blk >> 2, s = blk & 3;
    const int colbase = g * 64;
    for (int t = 0; t < Tn; ++t) {
      // wait: h0[t-1] complete (min fA0 >= t); reducer also ring-check fB0.
      {
        const bool ring = (s == 0) && (t + 1 > R0);
        for (;;) {
          int ok = 1;
          if (tid < 32) ok = (ldf(&fA0[tid]) >= (uint32_t)t);
          if (ring && tid >= 64 && tid < 96)
            ok &= (ldf(&fB0[tid - 64]) >= (uint32_t)(t + 1 - R0));
          if (__syncthreads_and(ok)) break;
          __builtin_amdgcn_s_sleep(1);
        }
        __builtin_amdgcn_fence(__ATOMIC_ACQUIRE, "workgroup");
      }
      const unsigned short* h0prev = h0ring + (size_t)((t + R0 - 1) % R0) * HSLOT;
      const unsigned short* xt = xall + (size_t)t * (Bn * En);
      f32x4 acc[2][4];
#pragma unroll
      for (int mt = 0; mt < 2; ++mt)
#pragma unroll
        for (int ct = 0; ct < 4; ++ct) acc[mt][ct] = (f32x4){0.f, 0.f, 0.f, 0.f};
#pragma unroll 4
      for (int kt = 0; kt < 20; ++kt) {
        const int kv = s * 640 + kt * 32;
        bf16x8 af0, af1;
        if (kv < 512) {  // x part: read-only, normal cached loads
          af0 = *reinterpret_cast<const bf16x8*>(xt + kv + (size_t)row0 * En + kq * 8);
          af1 = *reinterpret_cast<const bf16x8*>(xt + kv + (size_t)(row0 + 16) * En + kq * 8);
        } else {         // h part: fence-free agent atomics
          const unsigned short* hp = h0prev + (kv - 512);
          af0 = ld_h(hp + (size_t)row0 * Hn + kq * 8);
          af1 = ld_h(hp + (size_t)(row0 + 16) * Hn + kq * 8);
        }
#pragma unroll
        for (int ct = 0; ct < 4; ++ct) {
          bf16x8 bf = wlds[(kt * 4 + ct) * 64 + l];
          acc[0][ct] = __builtin_amdgcn_mfma_f32_16x16x32_bf16(af0, bf, acc[0][ct], 0, 0, 0);
          acc[1][ct] = __builtin_amdgcn_mfma_f32_16x16x32_bf16(af1, bf, acc[1][ct], 0, 0, 0);
        }
      }
      if (s != 0) {
        float* slot = pbufA + (size_t)blk * 8192;
#pragma unroll
        for (int mt = 0; mt < 2; ++mt)
#pragma unroll
          for (int ct = 0; ct < 4; ++ct)
            st_p(slot + ((w * 8 + mt * 4 + ct) * 256 + l * 4), acc[mt][ct]);
        drain_then_sync();
        if (tid == 0) stf(&fApart[blk], (uint32_t)(t + 1));
      } else {
        // wait partner partials
        for (;;) {
          int ok = 1;
          if (tid < 3) ok = (ldf(&fApart[blk + 1 + tid]) >= (uint32_t)(t + 1));
          if (__syncthreads_and(ok)) break;
          __builtin_amdgcn_s_sleep(1);
        }
        __builtin_amdgcn_fence(__ATOMIC_ACQUIRE, "workgroup");
        const float* p1 = pbufA + (size_t)(blk + 1) * 8192;
        const float* p2 = pbufA + (size_t)(blk + 2) * 8192;
        const float* p3 = pbufA + (size_t)(blk + 3) * 8192;
        unsigned short* h0cur = h0ring + (size_t)(t % R0) * HSLOT;
#pragma unroll
        for (int mt = 0; mt < 2; ++mt) {
#pragma unroll
          for (int ct = 0; ct < 4; ++ct) {
            const int base = (w * 8 + mt * 4 + ct) * 256 + l * 4;
            f32x4 sum = acc[mt][ct];
            sum += ld_p(p1 + base);
            sum += ld_p(p2 + base);
            sum += ld_p(p3 + base);
            const int col = colbase + ct * 16 + l15;
            const float bb = bias0[col];
#pragma unroll
            for (int r = 0; r < 4; ++r) {
              float v = tanhf(sum[r] + bb);
              int bo = f2b(v);
              int po = __shfl_down(bo, 1);
              if ((l15 & 1) == 0) {
                const int row = w * 32 + mt * 16 + kq * 4 + r;
                uint32_t packed = (uint32_t)(unsigned short)bo | ((uint32_t)(unsigned short)po << 16);
                stf((uint32_t*)(h0cur + (size_t)row * Hn + col), packed);
              }
            }
          }
        }
        drain_then_sync();
        if (tid == 0) stf(&fA0[g], (uint32_t)(t + 1));
      }
    }
  } else {
    const int bb = blk - 128;
    const int g = bb >> 2, s = bb & 3;
    const int colbase = g * 64;
    for (int t = 0; t < Tn; ++t) {
      {
        const bool ring = (s == 0) && (t + 2 > R1);
        for (;;) {
          int ok = 1;
          if (s < 2) {
            if (tid < 32) ok = (ldf(&fA0[tid]) >= (uint32_t)(t + 1));      // h0[t] done
            if (s == 1 && t > 0 && tid == 33)
              ok &= (ldf(&fB0[g]) >= (uint32_t)t);                         // pbuf consumed (race fix)
          } else {
            if (tid < 32) ok = (ldf(&fB0[tid]) >= (uint32_t)t);            // h1[t-1] done
          }
          if (ring && tid >= 64 && tid < 96)
            ok &= (ldf(&fB0[tid - 64]) >= (uint32_t)(t + 2 - R1));         // h1 ring safety
          if (__syncthreads_and(ok)) break;
          __builtin_amdgcn_s_sleep(1);
        }
        __builtin_amdgcn_fence(__ATOMIC_ACQUIRE, "workgroup");
      }
      const unsigned short* h0cur = h0ring + (size_t)(t % R0) * HSLOT;
      const unsigned short* h1prev = h1ring + (size_t)((t + R1 - 1) % R1) * HSLOT;
      const unsigned short* apbase;
      if (s == 0)      apbase = h0cur;
      else if (s == 1) apbase = h0cur + 1024;
      else if (s == 2) apbase = h1prev;
      else             apbase = h1prev + 1024;
      f32x4 acc[2][4];
#pragma unroll
      for (int mt = 0; mt < 2; ++mt)
#pragma unroll
        for (int ct = 0; ct < 4; ++ct) acc[mt][ct] = (f32x4){0.f, 0.f, 0.f, 0.f};
#pragma unroll 4
      for (int kt = 0; kt < 32; ++kt) {
        const unsigned short* ap = apbase + kt * 32;
        bf16x8 af0 = ld_h(ap + (size_t)row0 * Hn + kq * 8);
        bf16x8 af1 = ld_h(ap + (size_t)(row0 + 16) * Hn + kq * 8);
#pragma unroll
        for (int ct = 0; ct < 4; ++ct) {
          bf16x8 bf = wlds[(kt * 4 + ct) * 64 + l];
          acc[0][ct] = __builtin_amdgcn_mfma_f32_16x16x32_bf16(af0, bf, acc[0][ct], 0, 0, 0);
          acc[1][ct] = __builtin_amdgcn_mfma_f32_16x16x32_bf16(af1, bf, acc[1][ct], 0, 0, 0);
        }
      }
      if (s != 0) {
        float* slot = pbufB + (size_t)bb * 8192;
#pragma unroll
        for (int mt = 0; mt < 2; ++mt)
#pragma unroll
          for (int ct = 0; ct < 4; ++ct)
            st_p(slot + ((w * 8 + mt * 4 + ct) * 256 + l * 4), acc[mt][ct]);
        drain_then_sync();
        if (tid == 0) stf(&fBpart[bb], (uint32_t)(t + 1));
      } else {
        for (;;) {
          int ok = 1;
          if (tid < 3) ok = (ldf(&fBpart[bb + 1 + tid]) >= (uint32_t)(t + 1));
          if (__syncthreads_and(ok)) break;
          __builtin_amdgcn_s_sleep(1);
        }
        __builtin_amdgcn_fence(__ATOMIC_ACQUIRE, "workgroup");
        const float* p1 = pbufB + (size_t)(bb + 1) * 8192;
        const float* p2 = pbufB + (size_t)(bb + 2) * 8192;
        const float* p3 = pbufB + (size_t)(bb + 3) * 8192;
        unsigned short* h1cur = h1ring + (size_t)(t % R1) * HSLOT;
#pragma unroll
        for (int mt = 0; mt < 2; ++mt) {
#pragma unroll
          for (int ct = 0; ct < 4; ++ct) {
            const int base = (w * 8 + mt * 4 + ct) * 256 + l * 4;
            f32x4 sum = acc[mt][ct];
            sum += ld_p(p1 + base);
            sum += ld_p(p2 + base);
            sum += ld_p(p3 + base);
            const int col = colbase + ct * 16 + l15;
            const float bb2 = bias1[col];
#pragma unroll
            for (int r = 0; r < 4; ++r) {
              float v = tanhf(sum[r] + bb2);
              int bo = f2b(v);
              int po = __shfl_down(bo, 1);
              if ((l15 & 1) == 0) {
                const int row = w * 32 + mt * 16 + kq * 4 + r;
                uint32_t packed = (uint32_t)(unsigned short)bo | ((uint32_t)(unsigned short)po << 16);
                stf((uint32_t*)(h1cur + (size_t)row * Hn + col), packed);
              }
            }
          }
        }
        drain_then_sync();
        if (tid == 0) stf(&fB0[g], (uint32_t)(t + 1));
      }
    }
  }
}

// ---------------- head ----------------
// a1 = relu(h1 @ W1.T + b1)  [128 x 512] bf16
__global__ __launch_bounds__(256) void head1(const uint4* __restrict__ imgW1,
                                             const unsigned short* __restrict__ h1f,
                                             const float* __restrict__ b1,
                                             unsigned short* __restrict__ a1) {
  __shared__ uint4 smem[4096];
  const int tid = threadIdx.x;
  const int w = tid >> 6, l = tid & 63, l15 = l & 15, kq = l >> 4;
  const int g = blockIdx.x;  // 32
  const uint4* src = imgW1 + (size_t)g * 4096;
  for (int i = tid; i < 4096; i += 256) smem[i] = src[i];
  __syncthreads();
  const bf16x8* wlds = reinterpret_cast<const bf16x8*>(smem);
  const int row0 = w * 32 + l15;
  f32x4 acc[2];
  acc[0] = (f32x4){0.f, 0.f, 0.f, 0.f};
  acc[1] = (f32x4){0.f, 0.f, 0.f, 0.f};
#pragma unroll 4
  for (int kt = 0; kt < 64; ++kt) {
    bf16x8 af0 = *reinterpret_cast<const bf16x8*>(h1f + (size_t)row0 * Hn + kt * 32 + kq * 8);
    bf16x8 af1 = *reinterpret_cast<const bf16x8*>(h1f + (size_t)(row0 + 16) * Hn + kt * 32 + kq * 8);
    bf16x8 bf = wlds[kt * 64 + l];
    acc[0] = __builtin_amdgcn_mfma_f32_16x16x32_bf16(af0, bf, acc[0], 0, 0, 0);
    acc[1] = __builtin_amdgcn_mfma_f32_16x16x32_bf16(af1, bf, acc[1], 0, 0, 0);
  }
  const int col = g * 16 + l15;
  const float bb = b1[col];
#pragma unroll
  for (int mt = 0; mt < 2; ++mt)
#pragma unroll
    for (int r = 0; r < 4; ++r) {
      float v = fmaxf(acc[mt][r] + bb, 0.f);
      const int row = w * 32 + mt * 16 + kq * 4 + r;
      a1[(size_t)row * En + col] = f2b(v);
    }
}

// out = a1 @ W2.T + b2  [128 x 32000] f32
__global__ __launch_bounds__(256) void head2(const uint4* __restrict__ imgW2,
                                             const unsigned short* __restrict__ a1,
                                             const float* __restrict__ b2,
                                             float* __restrict__ out) {
  __shared__ uint4 smem[4096];
  const int tid = threadIdx.x;
  const int w = tid >> 6, l = tid & 63, l15 = l & 15, kq = l >> 4;
  const int g = blockIdx.x;  // 500
  const uint4* src = imgW2 + (size_t)g * 4096;
  for (int i = tid; i < 4096; i += 256) smem[i] = src[i];
  __syncthreads();
  const bf16x8* wlds = reinterpret_cast<const bf16x8*>(smem);
  const int row0 = w * 32 + l15;
  f32x4 acc[2][4];
#pragma unroll
  for (int mt = 0; mt < 2; ++mt)
#pragma unroll
    for (int ct = 0; ct < 4; ++ct) acc[mt][ct] = (f32x4){0.f, 0.f, 0.f, 0.f};
#pragma unroll
  for (int kt = 0; kt < 16; ++kt) {
    bf16x8 af0 = *reinterpret_cast<const bf16x8*>(a1 + (size_t)row0 * En + kt * 32 + kq * 8);
    bf16x8 af1 = *reinterpret_cast<const bf16x8*>(a1 + (size_t)(row0 + 16) * En + kt * 32 + kq * 8);
#pragma unroll
    for (int ct = 0; ct < 4; ++ct) {
      bf16x8 bf = wlds[(kt * 4 + ct) * 64 + l];
      acc[0][ct] = __builtin_amdgcn_mfma_f32_16x16x32_bf16(af0, bf, acc[0][ct], 0, 0, 0);
      acc[1][ct] = __builtin_amdgcn_mfma_f32_16x16x32_bf16(af1, bf, acc[1][ct], 0, 0, 0);
    }
  }
#pragma unroll
  for (int mt = 0; mt < 2; ++mt)
#pragma unroll
    for (int ct = 0; ct < 4; ++ct) {
      const int col = g * 64 + ct * 16 + l15;
      const float bb = b2[col];
#pragma unroll
      for (int r = 0; r < 4; ++r) {
        const int row = w * 32 + mt * 16 + kq * 4 + r;
        out[(size_t)row * Vn + col] = acc[mt][ct][r] + bb;
      }
    }
}

// ---------------- launch ----------------
extern "C" void kernel_launch(void* const* d_in, const int* in_sizes, int n_in,
                              void* d_out, int out_size, void* d_ws, size_t ws_size,
                              hipStream_t stream) {
  (void)in_sizes; (void)n_in; (void)out_size;
  const int* ids    = (const int*)d_in[0];
  const float* emb  = (const float*)d_in[1];
  const float* Wih0 = (const float*)d_in[2];
  const float* Whh0 = (const float*)d_in[3];
  const float* bih0 = (const float*)d_in[4];
  const float* bhh0 = (const float*)d_in[5];
  const float* Wih1 = (const float*)d_in[6];
  const float* Whh1 = (const float*)d_in[7];
  const float* bih1 = (const float*)d_in[8];
  const float* bhh1 = (const float*)d_in[9];
  const float* W1   = (const float*)d_in[10];
  const float* b1   = (const float*)d_in[11];
  const float* W2   = (const float*)d_in[12];
  const float* b2   = (const float*)d_in[13];
  float* out = (float*)d_out;

  char* ws = (char*)d_ws;
  size_t o = 0;
  auto alloc = [&](size_t bytes) -> char* {
    char* p = ws + o;
    o += (bytes + 255) & ~(size_t)255;
    return p;
  };
  uint32_t* flags = (uint32_t*)alloc(4096);
  float* bias0 = (float*)alloc(Hn * 4);
  float* bias1 = (float*)alloc(Hn * 4);
  unsigned short* h0ring = (unsigned short*)alloc((size_t)R0 * HSLOT * 2);
  unsigned short* h1ring = (unsigned short*)alloc((size_t)R1 * HSLOT * 2);
  float* pbufA = (float*)alloc(128ull * 8192 * 4);
  float* pbufB = (float*)alloc(128ull * 8192 * 4);
  unsigned short* a1 = (unsigned short*)alloc((size_t)Bn * En * 2);
  uint4* imgA  = (uint4*)alloc(128ull * 5120 * 16);
  uint4* imgB  = (uint4*)alloc(128ull * 8192 * 16);
  uint4* imgW1 = (uint4*)alloc(32ull * 4096 * 16);
  uint4* imgW2 = (uint4*)alloc(500ull * 4096 * 16);
  uint4* xall  = (uint4*)alloc((size_t)Tn * Bn * En * 2);
  if (o > ws_size) return;  // workspace too small -> fail visibly (no OOB writes)

  zero3<<<512, 256, 0, stream>>>(flags, 1024,
                                 (uint32_t*)(h0ring + (size_t)(R0 - 1) * HSLOT), 131072,
                                 (uint32_t*)(h1ring + (size_t)(R1 - 1) * HSLOT), 131072);
  pack_bias<<<8, 256, 0, stream>>>(bih0, bhh0, bih1, bhh1, bias0, bias1);
  pack_imgA<<<2560, 256, 0, stream>>>(Wih0, Whh0, imgA);
  pack_imgB<<<4096, 256, 0, stream>>>(Wih1, Whh1, imgB);
  pack_imgW1<<<512, 256, 0, stream>>>(W1, imgW1);
  pack_imgW2<<<8000, 256, 0, stream>>>(W2, imgW2);
  gather_x<<<16384, 256, 0, stream>>>(ids, emb, xall);

  rnn_persist<<<256, 256, 0, stream>>>(imgA, imgB, (const unsigned short*)xall,
                                       h0ring, h1ring, pbufA, pbufB, bias0, bias1, flags);

  head1<<<32, 256, 0, stream>>>(imgW1, h1ring + (size_t)(511 % R1) * HSLOT, b1, a1);
  head2<<<500, 256, 0, stream>>>(imgW2, a1, b2, out);
}

// Round 4
// 14101.945 us; speedup vs baseline: 2.2494x; 1.0692x over previous
//
#include <hip/hip_runtime.h>
#include <hip/hip_bf16.h>
#include <stdint.h>

// Problem dims
#define Bn 128
#define Tn 512
#define En 512
#define Hn 2048
#define Vn 32000
#define R0 8           // h0 ring depth
#define R1 4           // h1 ring depth
#define HSLOT (Bn*Hn)  // elements per h slot

typedef float f32x4 __attribute__((ext_vector_type(4)));
typedef short bf16x8 __attribute__((ext_vector_type(8)));
typedef unsigned long long u64;

__device__ __forceinline__ unsigned short f2b(float f) {
  // round-to-nearest-even bf16
  uint32_t x = __builtin_bit_cast(uint32_t, f);
  uint32_t r = x + 0x7FFFu + ((x >> 16) & 1u);
  return (unsigned short)(r >> 16);
}

// ---- fence-free cross-XCD data movement: relaxed agent-scope atomics ----
// These bypass the non-coherent per-XCD L2 to the coherence point (MALL), so
// producer->consumer visibility needs NO wbl2/inv. Ordering data-before-flag
// is enforced by s_waitcnt vmcnt(0) + __syncthreads before the flag store.
union U16x8 { bf16x8 v; u64 q[2]; };
union F32x4u { f32x4 v; u64 q[2]; };

__device__ __forceinline__ bf16x8 ld_h(const unsigned short* p) {
  U16x8 u;
  u.q[0] = __hip_atomic_load((const u64*)p,     __ATOMIC_RELAXED, __HIP_MEMORY_SCOPE_AGENT);
  u.q[1] = __hip_atomic_load((const u64*)p + 1, __ATOMIC_RELAXED, __HIP_MEMORY_SCOPE_AGENT);
  return u.v;
}
__device__ __forceinline__ f32x4 ld_p(const float* p) {
  F32x4u u;
  u.q[0] = __hip_atomic_load((const u64*)p,     __ATOMIC_RELAXED, __HIP_MEMORY_SCOPE_AGENT);
  u.q[1] = __hip_atomic_load((const u64*)p + 1, __ATOMIC_RELAXED, __HIP_MEMORY_SCOPE_AGENT);
  return u.v;
}
__device__ __forceinline__ void st_p(float* p, f32x4 x) {
  F32x4u u; u.v = x;
  __hip_atomic_store((u64*)p,     u.q[0], __ATOMIC_RELAXED, __HIP_MEMORY_SCOPE_AGENT);
  __hip_atomic_store((u64*)p + 1, u.q[1], __ATOMIC_RELAXED, __HIP_MEMORY_SCOPE_AGENT);
}
__device__ __forceinline__ uint32_t ldf(const uint32_t* p) {
  return __hip_atomic_load(p, __ATOMIC_RELAXED, __HIP_MEMORY_SCOPE_AGENT);
}
__device__ __forceinline__ void stf(uint32_t* p, uint32_t v) {
  __hip_atomic_store(p, v, __ATOMIC_RELAXED, __HIP_MEMORY_SCOPE_AGENT);
}
__device__ __forceinline__ void drain_then_sync() {
  asm volatile("s_waitcnt vmcnt(0)" ::: "memory");
  __syncthreads();
}

// Flag layout (u32 indices into `flags`), anti-hotspot replicated:
//   rep r in 0..7 at base r*1024 (4 KiB apart -> distinct MALL banks):
//     [r*1024 +  0 .. +31]  fA0 replica r  (group g's h0 step count)
//     [r*1024 + 64 .. +95]  fB0 replica r  (group g's h1 step count)
//   [8192 + g*16 + s]  fApart: role-A partial s of group g wrote pbuf (1 producer, 1 poller)
//   [9216 + g*16 + s]  fBpart: role-B partial s of group g
#define NREP 8
#define FA_PART_BASE 8192
#define FB_PART_BASE 9216
#define FLAG_WORDS 16384

// ---------------- init / pack kernels ----------------

__global__ void zero3(uint32_t* a, int na, uint32_t* b, int nb, uint32_t* c, int nc) {
  int i = blockIdx.x * 256 + threadIdx.x;
  if (i < na) a[i] = 0u;
  if (i < nb) b[i] = 0u;
  if (i < nc) c[i] = 0u;
}

__global__ void pack_bias(const float* bih0, const float* bhh0,
                          const float* bih1, const float* bhh1,
                          float* bias0, float* bias1) {
  int i = blockIdx.x * 256 + threadIdx.x;  // 2048 threads
  bias0[i] = bih0[i] + bhh0[i];
  bias1[i] = bih1[i] + bhh1[i];
}

// A-images: 128 WGs x 5120 packets of 16B. packet p=(kt*4+ct)*64+l
// element j of lane l: W[col = g*64+ct*16+(l&15)][kv = s*640+kt*32+(l>>4)*8+j]
// kv<512 -> Wih0 [H x E], else Whh0 [H x H] at kv-512
__global__ void pack_imgA(const float* __restrict__ Wih0, const float* __restrict__ Whh0,
                          uint4* __restrict__ imgA) {
  int tid = blockIdx.x * 256 + threadIdx.x;   // 655360 total
  int wg = tid / 5120;
  int p  = tid - wg * 5120;
  int l = p & 63;
  int ckt = p >> 6;
  int ct = ckt & 3, kt = ckt >> 2;
  int g = wg >> 2, s = wg & 3;
  int col = g * 64 + ct * 16 + (l & 15);
  int kv0 = s * 640 + kt * 32 + (l >> 4) * 8;
  const float* src = (kv0 < 512) ? (Wih0 + (size_t)col * En + kv0)
                                 : (Whh0 + (size_t)col * Hn + (kv0 - 512));
  unsigned short o[8];
#pragma unroll
  for (int j = 0; j < 8; ++j) o[j] = f2b(src[j]);
  imgA[tid] = *reinterpret_cast<uint4*>(o);
}

// B-images: 128 WGs x 8192 packets. kv = s*1024+kt*32+..; kv<2048 -> Wih1 else Whh1
__global__ void pack_imgB(const float* __restrict__ Wih1, const float* __restrict__ Whh1,
                          uint4* __restrict__ imgB) {
  int tid = blockIdx.x * 256 + threadIdx.x;   // 1048576 total
  int wg = tid >> 13;
  int p  = tid & 8191;
  int l = p & 63;
  int ckt = p >> 6;
  int ct = ckt & 3, kt = ckt >> 2;
  int g = wg >> 2, s = wg & 3;
  int col = g * 64 + ct * 16 + (l & 15);
  int kv0 = s * 1024 + kt * 32 + (l >> 4) * 8;
  const float* src = (kv0 < 2048) ? (Wih1 + (size_t)col * Hn + kv0)
                                  : (Whh1 + (size_t)col * Hn + (kv0 - 2048));
  unsigned short o[8];
#pragma unroll
  for (int j = 0; j < 8; ++j) o[j] = f2b(src[j]);
  imgB[tid] = *reinterpret_cast<uint4*>(o);
}

// W1 images: 32 groups of 16 cols, K=2048: 4096 packets each (kt*64+l)
__global__ void pack_imgW1(const float* __restrict__ W1, uint4* __restrict__ img) {
  int tid = blockIdx.x * 256 + threadIdx.x;  // 131072
  int grp = tid >> 12;
  int p = tid & 4095;
  int l = p & 63;
  int kt = p >> 6;
  int col = grp * 16 + (l & 15);
  int k0 = kt * 32 + (l >> 4) * 8;
  const float* src = W1 + (size_t)col * Hn + k0;
  unsigned short o[8];
#pragma unroll
  for (int j = 0; j < 8; ++j) o[j] = f2b(src[j]);
  img[tid] = *reinterpret_cast<uint4*>(o);
}

// W2 images: 500 groups of 64 cols, K=512: 4096 packets each ((kt*4+ct)*64+l)
__global__ void pack_imgW2(const float* __restrict__ W2, uint4* __restrict__ img) {
  int tid = blockIdx.x * 256 + threadIdx.x;  // 2048000
  int grp = tid >> 12;
  int p = tid & 4095;
  int l = p & 63;
  int ckt = p >> 6;
  int ct = ckt & 3, kt = ckt >> 2;
  int col = grp * 64 + ct * 16 + (l & 15);
  int k0 = kt * 32 + (l >> 4) * 8;
  const float* src = W2 + (size_t)col * En + k0;
  unsigned short o[8];
#pragma unroll
  for (int j = 0; j < 8; ++j) o[j] = f2b(src[j]);
  img[tid] = *reinterpret_cast<uint4*>(o);
}

// x_all[t][b][e] bf16 = emb[ids[b][t]][e]
__global__ void gather_x(const int* __restrict__ ids, const float* __restrict__ emb,
                         uint4* __restrict__ xall) {
  int tid = blockIdx.x * 256 + threadIdx.x;  // 4194304
  int t = tid >> 13;
  int r = tid & 8191;
  int b = r >> 6;
  int e8 = r & 63;
  int id = ids[b * Tn + t];
  const float* src = emb + (size_t)id * En + e8 * 8;
  unsigned short o[8];
#pragma unroll
  for (int j = 0; j < 8; ++j) o[j] = f2b(src[j]);
  xall[tid] = *reinterpret_cast<uint4*>(o);
}

// ---------------- persistent RNN kernel ----------------
// blocks 0..127  : role A (h0). group g=blk>>2 owns cols [g*64,g*64+64), split s=blk&3
//                  K-chunk = virtual k [s*640, s*640+640) of [x_t(512) ; h0(t-1)(2048)]
// blocks 128..255: role B (h1). K-chunk = [s*1024, ..) of [h0(t)(2048) ; h1(t-1)(2048)]
// Waits = round-3 audited set (incl. s==1 race fix + ring checks), over replicated flags.
__global__ __launch_bounds__(256) void rnn_persist(
    const uint4* __restrict__ imgA, const uint4* __restrict__ imgB,
    const unsigned short* __restrict__ xall,
    unsigned short* __restrict__ h0ring, unsigned short* __restrict__ h1ring,
    float* __restrict__ pbufA, float* __restrict__ pbufB,
    const float* __restrict__ bias0, const float* __restrict__ bias1,
    uint32_t* flags) {
  __shared__ uint4 smem[8192];  // 128 KiB -> 1 WG/CU, 256 WGs = 256 CUs, all resident
  const int tid = threadIdx.x;
  const int w = tid >> 6;
  const int l = tid & 63;
  const int l15 = l & 15;
  const int kq = l >> 4;
  const int blk = blockIdx.x;
  const int myrep = blk & (NREP - 1);
  const uint32_t* fA0r = flags + (size_t)myrep * 1024;
  const uint32_t* fB0r = flags + (size_t)myrep * 1024 + 64;
  uint32_t* fApart = flags + FA_PART_BASE;
  uint32_t* fBpart = flags + FB_PART_BASE;

  const bool roleA = (blk < 128);
  {
    const uint4* src = roleA ? (imgA + (size_t)blk * 5120) : (imgB + (size_t)(blk - 128) * 8192);
    const int n = roleA ? 5120 : 8192;
    for (int i = tid; i < n; i += 256) smem[i] = src[i];
  }
  __syncthreads();
  const bf16x8* wlds = reinterpret_cast<const bf16x8*>(smem);
  const int row0 = w * 32 + l15;

  if (roleA) {
    const int g = blk >> 2, s = blk & 3;
    const int colbase = g * 64;
    for (int t = 0; t < Tn; ++t) {
      // wait: h0[t-1] complete (min fA0 >= t); reducer also ring-check fB0.
      {
        const bool ring = (s == 0) && (t + 1 > R0);
        for (;;) {
          int ok = 1;
          if (tid < 32) ok = (ldf(&fA0r[tid]) >= (uint32_t)t);
          if (ring && tid >= 64 && tid < 96)
            ok &= (ldf(&fB0r[tid - 64]) >= (uint32_t)(t + 1 - R0));
          if (__syncthreads_and(ok)) break;
          __builtin_amdgcn_s_sleep(2);
        }
        __builtin_amdgcn_fence(__ATOMIC_ACQUIRE, "workgroup");
      }
      const unsigned short* h0prev = h0ring + (size_t)((t + R0 - 1) % R0) * HSLOT;
      const unsigned short* xt = xall + (size_t)t * (Bn * En);
      f32x4 acc[2][4];
#pragma unroll
      for (int mt = 0; mt < 2; ++mt)
#pragma unroll
        for (int ct = 0; ct < 4; ++ct) acc[mt][ct] = (f32x4){0.f, 0.f, 0.f, 0.f};
#pragma unroll 4
      for (int kt = 0; kt < 20; ++kt) {
        const int kv = s * 640 + kt * 32;
        bf16x8 af0, af1;
        if (kv < 512) {  // x part: read-only, normal cached loads
          af0 = *reinterpret_cast<const bf16x8*>(xt + kv + (size_t)row0 * En + kq * 8);
          af1 = *reinterpret_cast<const bf16x8*>(xt + kv + (size_t)(row0 + 16) * En + kq * 8);
        } else {         // h part: fence-free MALL atomics
          const unsigned short* hp = h0prev + (kv - 512);
          af0 = ld_h(hp + (size_t)row0 * Hn + kq * 8);
          af1 = ld_h(hp + (size_t)(row0 + 16) * Hn + kq * 8);
        }
#pragma unroll
        for (int ct = 0; ct < 4; ++ct) {
          bf16x8 bf = wlds[(kt * 4 + ct) * 64 + l];
          acc[0][ct] = __builtin_amdgcn_mfma_f32_16x16x32_bf16(af0, bf, acc[0][ct], 0, 0, 0);
          acc[1][ct] = __builtin_amdgcn_mfma_f32_16x16x32_bf16(af1, bf, acc[1][ct], 0, 0, 0);
        }
      }
      if (s != 0) {
        float* slot = pbufA + (size_t)blk * 8192;
#pragma unroll
        for (int mt = 0; mt < 2; ++mt)
#pragma unroll
          for (int ct = 0; ct < 4; ++ct)
            st_p(slot + ((w * 8 + mt * 4 + ct) * 256 + l * 4), acc[mt][ct]);
        drain_then_sync();
        if (tid == 0) stf(&fApart[g * 16 + s], (uint32_t)(t + 1));
      } else {
        // wait partner partials (private line, single poller)
        for (;;) {
          int ok = 1;
          if (tid < 3) ok = (ldf(&fApart[g * 16 + 1 + tid]) >= (uint32_t)(t + 1));
          if (__syncthreads_and(ok)) break;
          __builtin_amdgcn_s_sleep(2);
        }
        __builtin_amdgcn_fence(__ATOMIC_ACQUIRE, "workgroup");
        const float* p1 = pbufA + (size_t)(blk + 1) * 8192;
        const float* p2 = pbufA + (size_t)(blk + 2) * 8192;
        const float* p3 = pbufA + (size_t)(blk + 3) * 8192;
        unsigned short* h0cur = h0ring + (size_t)(t % R0) * HSLOT;
#pragma unroll
        for (int mt = 0; mt < 2; ++mt) {
#pragma unroll
          for (int ct = 0; ct < 4; ++ct) {
            const int base = (w * 8 + mt * 4 + ct) * 256 + l * 4;
            f32x4 sum = acc[mt][ct];
            sum += ld_p(p1 + base);
            sum += ld_p(p2 + base);
            sum += ld_p(p3 + base);
            const int col = colbase + ct * 16 + l15;
            const float bb = bias0[col];
#pragma unroll
            for (int r = 0; r < 4; ++r) {
              float v = tanhf(sum[r] + bb);
              int bo = f2b(v);
              int po = __shfl_down(bo, 1);
              if ((l15 & 1) == 0) {
                const int row = w * 32 + mt * 16 + kq * 4 + r;
                uint32_t packed = (uint32_t)(unsigned short)bo | ((uint32_t)(unsigned short)po << 16);
                stf((uint32_t*)(h0cur + (size_t)row * Hn + col), packed);
              }
            }
          }
        }
        drain_then_sync();
        if (tid < NREP) stf(flags + (size_t)tid * 1024 + g, (uint32_t)(t + 1));  // fA0 replicas
      }
    }
  } else {
    const int bb = blk - 128;
    const int g = bb >> 2, s = bb & 3;
    const int colbase = g * 64;
    for (int t = 0; t < Tn; ++t) {
      {
        const bool ring = (s == 0) && (t + 2 > R1);
        for (;;) {
          int ok = 1;
          if (s < 2) {
            if (tid < 32) ok = (ldf(&fA0r[tid]) >= (uint32_t)(t + 1));     // h0[t] done
            if (s == 1 && t > 0 && tid == 33)
              ok &= (ldf(&fB0r[g]) >= (uint32_t)t);                        // pbuf consumed (race fix)
          } else {
            if (tid < 32) ok = (ldf(&fB0r[tid]) >= (uint32_t)t);           // h1[t-1] done
          }
          if (ring && tid >= 64 && tid < 96)
            ok &= (ldf(&fB0r[tid - 64]) >= (uint32_t)(t + 2 - R1));        // h1 ring safety
          if (__syncthreads_and(ok)) break;
          __builtin_amdgcn_s_sleep(2);
        }
        __builtin_amdgcn_fence(__ATOMIC_ACQUIRE, "workgroup");
      }
      const unsigned short* h0cur = h0ring + (size_t)(t % R0) * HSLOT;
      const unsigned short* h1prev = h1ring + (size_t)((t + R1 - 1) % R1) * HSLOT;
      const unsigned short* apbase;
      if (s == 0)      apbase = h0cur;
      else if (s == 1) apbase = h0cur + 1024;
      else if (s == 2) apbase = h1prev;
      else             apbase = h1prev + 1024;
      f32x4 acc[2][4];
#pragma unroll
      for (int mt = 0; mt < 2; ++mt)
#pragma unroll
        for (int ct = 0; ct < 4; ++ct) acc[mt][ct] = (f32x4){0.f, 0.f, 0.f, 0.f};
#pragma unroll 4
      for (int kt = 0; kt < 32; ++kt) {
        const unsigned short* ap = apbase + kt * 32;
        bf16x8 af0 = ld_h(ap + (size_t)row0 * Hn + kq * 8);
        bf16x8 af1 = ld_h(ap + (size_t)(row0 + 16) * Hn + kq * 8);
#pragma unroll
        for (int ct = 0; ct < 4; ++ct) {
          bf16x8 bf = wlds[(kt * 4 + ct) * 64 + l];
          acc[0][ct] = __builtin_amdgcn_mfma_f32_16x16x32_bf16(af0, bf, acc[0][ct], 0, 0, 0);
          acc[1][ct] = __builtin_amdgcn_mfma_f32_16x16x32_bf16(af1, bf, acc[1][ct], 0, 0, 0);
        }
      }
      if (s != 0) {
        float* slot = pbufB + (size_t)bb * 8192;
#pragma unroll
        for (int mt = 0; mt < 2; ++mt)
#pragma unroll
          for (int ct = 0; ct < 4; ++ct)
            st_p(slot + ((w * 8 + mt * 4 + ct) * 256 + l * 4), acc[mt][ct]);
        drain_then_sync();
        if (tid == 0) stf(&fBpart[g * 16 + s], (uint32_t)(t + 1));
      } else {
        for (;;) {
          int ok = 1;
          if (tid < 3) ok = (ldf(&fBpart[g * 16 + 1 + tid]) >= (uint32_t)(t + 1));
          if (__syncthreads_and(ok)) break;
          __builtin_amdgcn_s_sleep(2);
        }
        __builtin_amdgcn_fence(__ATOMIC_ACQUIRE, "workgroup");
        const float* p1 = pbufB + (size_t)(bb + 1) * 8192;
        const float* p2 = pbufB + (size_t)(bb + 2) * 8192;
        const float* p3 = pbufB + (size_t)(bb + 3) * 8192;
        unsigned short* h1cur = h1ring + (size_t)(t % R1) * HSLOT;
#pragma unroll
        for (int mt = 0; mt < 2; ++mt) {
#pragma unroll
          for (int ct = 0; ct < 4; ++ct) {
            const int base = (w * 8 + mt * 4 + ct) * 256 + l * 4;
            f32x4 sum = acc[mt][ct];
            sum += ld_p(p1 + base);
            sum += ld_p(p2 + base);
            sum += ld_p(p3 + base);
            const int col = colbase + ct * 16 + l15;
            const float bb2 = bias1[col];
#pragma unroll
            for (int r = 0; r < 4; ++r) {
              float v = tanhf(sum[r] + bb2);
              int bo = f2b(v);
              int po = __shfl_down(bo, 1);
              if ((l15 & 1) == 0) {
                const int row = w * 32 + mt * 16 + kq * 4 + r;
                uint32_t packed = (uint32_t)(unsigned short)bo | ((uint32_t)(unsigned short)po << 16);
                stf((uint32_t*)(h1cur + (size_t)row * Hn + col), packed);
              }
            }
          }
        }
        drain_then_sync();
        if (tid < NREP) stf(flags + (size_t)tid * 1024 + 64 + g, (uint32_t)(t + 1));  // fB0 replicas
      }
    }
  }
}

// ---------------- head ----------------
// a1 = relu(h1 @ W1.T + b1)  [128 x 512] bf16
__global__ __launch_bounds__(256) void head1(const uint4* __restrict__ imgW1,
                                             const unsigned short* __restrict__ h1f,
                                             const float* __restrict__ b1,
                                             unsigned short* __restrict__ a1) {
  __shared__ uint4 smem[4096];
  const int tid = threadIdx.x;
  const int w = tid >> 6, l = tid & 63, l15 = l & 15, kq = l >> 4;
  const int g = blockIdx.x;  // 32
  const uint4* src = imgW1 + (size_t)g * 4096;
  for (int i = tid; i < 4096; i += 256) smem[i] = src[i];
  __syncthreads();
  const bf16x8* wlds = reinterpret_cast<const bf16x8*>(smem);
  const int row0 = w * 32 + l15;
  f32x4 acc[2];
  acc[0] = (f32x4){0.f, 0.f, 0.f, 0.f};
  acc[1] = (f32x4){0.f, 0.f, 0.f, 0.f};
#pragma unroll 4
  for (int kt = 0; kt < 64; ++kt) {
    bf16x8 af0 = *reinterpret_cast<const bf16x8*>(h1f + (size_t)row0 * Hn + kt * 32 + kq * 8);
    bf16x8 af1 = *reinterpret_cast<const bf16x8*>(h1f + (size_t)(row0 + 16) * Hn + kt * 32 + kq * 8);
    bf16x8 bf = wlds[kt * 64 + l];
    acc[0] = __builtin_amdgcn_mfma_f32_16x16x32_bf16(af0, bf, acc[0], 0, 0, 0);
    acc[1] = __builtin_amdgcn_mfma_f32_16x16x32_bf16(af1, bf, acc[1], 0, 0, 0);
  }
  const int col = g * 16 + l15;
  const float bb = b1[col];
#pragma unroll
  for (int mt = 0; mt < 2; ++mt)
#pragma unroll
    for (int r = 0; r < 4; ++r) {
      float v = fmaxf(acc[mt][r] + bb, 0.f);
      const int row = w * 32 + mt * 16 + kq * 4 + r;
      a1[(size_t)row * En + col] = f2b(v);
    }
}

// out = a1 @ W2.T + b2  [128 x 32000] f32
__global__ __launch_bounds__(256) void head2(const uint4* __restrict__ imgW2,
                                             const unsigned short* __restrict__ a1,
                                             const float* __restrict__ b2,
                                             float* __restrict__ out) {
  __shared__ uint4 smem[4096];
  const int tid = threadIdx.x;
  const int w = tid >> 6, l = tid & 63, l15 = l & 15, kq = l >> 4;
  const int g = blockIdx.x;  // 500
  const uint4* src = imgW2 + (size_t)g * 4096;
  for (int i = tid; i < 4096; i += 256) smem[i] = src[i];
  __syncthreads();
  const bf16x8* wlds = reinterpret_cast<const bf16x8*>(smem);
  const int row0 = w * 32 + l15;
  f32x4 acc[2][4];
#pragma unroll
  for (int mt = 0; mt < 2; ++mt)
#pragma unroll
    for (int ct = 0; ct < 4; ++ct) acc[mt][ct] = (f32x4){0.f, 0.f, 0.f, 0.f};
#pragma unroll
  for (int kt = 0; kt < 16; ++kt) {
    bf16x8 af0 = *reinterpret_cast<const bf16x8*>(a1 + (size_t)row0 * En + kt * 32 + kq * 8);
    bf16x8 af1 = *reinterpret_cast<const bf16x8*>(a1 + (size_t)(row0 + 16) * En + kt * 32 + kq * 8);
#pragma unroll
    for (int ct = 0; ct < 4; ++ct) {
      bf16x8 bf = wlds[(kt * 4 + ct) * 64 + l];
      acc[0][ct] = __builtin_amdgcn_mfma_f32_16x16x32_bf16(af0, bf, acc[0][ct], 0, 0, 0);
      acc[1][ct] = __builtin_amdgcn_mfma_f32_16x16x32_bf16(af1, bf, acc[1][ct], 0, 0, 0);
    }
  }
#pragma unroll
  for (int mt = 0; mt < 2; ++mt)
#pragma unroll
    for (int ct = 0; ct < 4; ++ct) {
      const int col = g * 64 + ct * 16 + l15;
      const float bb = b2[col];
#pragma unroll
      for (int r = 0; r < 4; ++r) {
        const int row = w * 32 + mt * 16 + kq * 4 + r;
        out[(size_t)row * Vn + col] = acc[mt][ct][r] + bb;
      }
    }
}

// ---------------- launch ----------------
extern "C" void kernel_launch(void* const* d_in, const int* in_sizes, int n_in,
                              void* d_out, int out_size, void* d_ws, size_t ws_size,
                              hipStream_t stream) {
  (void)in_sizes; (void)n_in; (void)out_size;
  const int* ids    = (const int*)d_in[0];
  const float* emb  = (const float*)d_in[1];
  const float* Wih0 = (const float*)d_in[2];
  const float* Whh0 = (const float*)d_in[3];
  const float* bih0 = (const float*)d_in[4];
  const float* bhh0 = (const float*)d_in[5];
  const float* Wih1 = (const float*)d_in[6];
  const float* Whh1 = (const float*)d_in[7];
  const float* bih1 = (const float*)d_in[8];
  const float* bhh1 = (const float*)d_in[9];
  const float* W1   = (const float*)d_in[10];
  const float* b1   = (const float*)d_in[11];
  const float* W2   = (const float*)d_in[12];
  const float* b2   = (const float*)d_in[13];
  float* out = (float*)d_out;

  char* ws = (char*)d_ws;
  size_t o = 0;
  auto alloc = [&](size_t bytes) -> char* {
    char* p = ws + o;
    o += (bytes + 255) & ~(size_t)255;
    return p;
  };
  uint32_t* flags = (uint32_t*)alloc(FLAG_WORDS * 4);
  float* bias0 = (float*)alloc(Hn * 4);
  float* bias1 = (float*)alloc(Hn * 4);
  unsigned short* h0ring = (unsigned short*)alloc((size_t)R0 * HSLOT * 2);
  unsigned short* h1ring = (unsigned short*)alloc((size_t)R1 * HSLOT * 2);
  float* pbufA = (float*)alloc(128ull * 8192 * 4);
  float* pbufB = (float*)alloc(128ull * 8192 * 4);
  unsigned short* a1 = (unsigned short*)alloc((size_t)Bn * En * 2);
  uint4* imgA  = (uint4*)alloc(128ull * 5120 * 16);
  uint4* imgB  = (uint4*)alloc(128ull * 8192 * 16);
  uint4* imgW1 = (uint4*)alloc(32ull * 4096 * 16);
  uint4* imgW2 = (uint4*)alloc(500ull * 4096 * 16);
  uint4* xall  = (uint4*)alloc((size_t)Tn * Bn * En * 2);
  if (o > ws_size) return;  // workspace too small -> fail visibly (no OOB writes)

  zero3<<<512, 256, 0, stream>>>(flags, FLAG_WORDS,
                                 (uint32_t*)(h0ring + (size_t)(R0 - 1) * HSLOT), 131072,
                                 (uint32_t*)(h1ring + (size_t)(R1 - 1) * HSLOT), 131072);
  pack_bias<<<8, 256, 0, stream>>>(bih0, bhh0, bih1, bhh1, bias0, bias1);
  pack_imgA<<<2560, 256, 0, stream>>>(Wih0, Whh0, imgA);
  pack_imgB<<<4096, 256, 0, stream>>>(Wih1, Whh1, imgB);
  pack_imgW1<<<512, 256, 0, stream>>>(W1, imgW1);
  pack_imgW2<<<8000, 256, 0, stream>>>(W2, imgW2);
  gather_x<<<16384, 256, 0, stream>>>(ids, emb, xall);

  rnn_persist<<<256, 256, 0, stream>>>(imgA, imgB, (const unsigned short*)xall,
                                       h0ring, h1ring, pbufA, pbufB, bias0, bias1, flags);

  head1<<<32, 256, 0, stream>>>(imgW1, h1ring + (size_t)(511 % R1) * HSLOT, b1, a1);
  head2<<<500, 256, 0, stream>>>(imgW2, a1, b2, out);
}